// Round 6
// baseline (220.003 us; speedup 1.0000x reference)
//
#include <hip/hip_runtime.h>
#include <hip/hip_bf16.h>
#include <cstdint>
#include <cstddef>

#define DEVI __device__ __forceinline__

typedef __attribute__((ext_vector_type(8))) short bf16x8;   // 8 bf16 in 4 VGPRs (guide §3)
typedef __attribute__((ext_vector_type(4))) float f32x4;
typedef __attribute__((ext_vector_type(8))) unsigned short u16x8;

// round-to-nearest-even f32 -> bf16 bits
DEVI unsigned short f2bf(float f) {
  union { float f; unsigned int u; } v; v.f = f;
  unsigned int r = v.u + 0x7FFFu + ((v.u >> 16) & 1u);
  return (unsigned short)(r >> 16);
}

DEVI void gload_lds16(const void* g, void* l) {
  __builtin_amdgcn_global_load_lds((const __attribute__((address_space(1))) void*)g,
                                   (__attribute__((address_space(3))) void*)l,
                                   16, 0, 0);
}

// ---------------- prep: f32 -> bf16 convert (vectorized) ----------------
__global__ void cvt_k(const float* __restrict__ in, unsigned short* __restrict__ out, int n4) {
  int i = blockIdx.x * 256 + threadIdx.x;
  if (i >= n4) return;
  float4 v = reinterpret_cast<const float4*>(in)[i];
  ushort4 o;
  o.x = f2bf(v.x); o.y = f2bf(v.y); o.z = f2bf(v.z); o.w = f2bf(v.w);
  reinterpret_cast<ushort4*>(out)[i] = o;
}

// ---------------- prep: W_eff = W_qkv + 2 * B @ A  (LoRA folded) ----------------
__global__ void weff_k(const float* __restrict__ W,
                       const float* __restrict__ Aq, const float* __restrict__ Bq,
                       const float* __restrict__ Ak, const float* __restrict__ Bk,
                       const float* __restrict__ Av, const float* __restrict__ Bv,
                       unsigned short* __restrict__ out) {
  int idx = blockIdx.x * 256 + threadIdx.x;   // 3072*1024 total
  int o = idx >> 10, c = idx & 1023;
  const float* A; const float* B; int ol;
  if (o < 1024)      { A = Aq; B = Bq; ol = o; }
  else if (o < 2048) { A = Ak; B = Bk; ol = o - 1024; }
  else               { A = Av; B = Bv; ol = o - 2048; }
  float acc = W[idx];
#pragma unroll
  for (int r = 0; r < 8; ++r) acc += 2.0f * B[ol*8 + r] * A[r*1024 + c];
  out[idx] = f2bf(acc);
}

// ---------------- GEMM: C[M,NCOLS] = A[M,1024] * Bw[NCOLS,1024]^T ----------------
// EPI=0: +bias, l2-normalize q/k over 64-col head chunks, scatter to [N,H,L,64] bf16
// EPI=1: +bias, write fp32 [M,NCOLS]
template<int NCOLS, int EPI>
__global__ __launch_bounds__(256)
void gemm_k(const unsigned short* __restrict__ A,
            const unsigned short* __restrict__ Bw,
            const float* __restrict__ bias,
            unsigned short* __restrict__ q_out,
            unsigned short* __restrict__ k_out,
            unsigned short* __restrict__ v_out,
            float* __restrict__ f_out)
{
  constexpr int K = 1024;
  constexpr int NBN = NCOLS / 128;
  __shared__ unsigned short As[128*32];   // 8 KB, row-major [128][32] bf16
  __shared__ unsigned short Bs[128*32];
  const int bid  = blockIdx.x;
  const int bn   = bid % NBN, bm = bid / NBN;
  const int tid  = threadIdx.x;
  const int lane = tid & 63, wave = tid >> 6;
  const int wr = wave >> 1, wc = wave & 1;     // 2x2 wave grid, 64x64 each
  const int l15 = lane & 15, g = lane >> 4;

  const f32x4 fzero = {0.f, 0.f, 0.f, 0.f};
  f32x4 acc[4][4];
#pragma unroll
  for (int m = 0; m < 4; ++m)
#pragma unroll
    for (int n = 0; n < 4; ++n) acc[m][n] = fzero;

  for (int k0 = 0; k0 < K; k0 += 32) {
#pragma unroll
    for (int j = 0; j < 2; ++j) {
      int off = j*4096 + tid*16;            // linear byte offset in 8KB tile
      int r = off >> 6, cb = off & 63;      // row (64B rows), col byte
      gload_lds16((const char*)(A  + (size_t)(bm*128 + r) * K) + k0*2 + cb, (char*)As + off);
      gload_lds16((const char*)(Bw + (size_t)(bn*128 + r) * K) + k0*2 + cb, (char*)Bs + off);
    }
    __syncthreads();   // drains vmcnt for global_load_lds
    bf16x8 af[4], bfr[4];
#pragma unroll
    for (int m = 0; m < 4; ++m)
      af[m] = *(const bf16x8*)((const char*)As + (wr*64 + m*16 + l15)*64 + g*16);
#pragma unroll
    for (int n = 0; n < 4; ++n)
      bfr[n] = *(const bf16x8*)((const char*)Bs + (wc*64 + n*16 + l15)*64 + g*16);
#pragma unroll
    for (int m = 0; m < 4; ++m)
#pragma unroll
      for (int n = 0; n < 4; ++n)
        acc[m][n] = __builtin_amdgcn_mfma_f32_16x16x32_bf16(af[m], bfr[n], acc[m][n], 0, 0, 0);
    __syncthreads();
  }

  const int colBase = bn*128 + wc*64;   // one 64-col head chunk per wave
  const int rBase   = bm*128 + wr*64;
  float bias_n[4];
#pragma unroll
  for (int n = 0; n < 4; ++n) bias_n[n] = bias[colBase + n*16 + l15];
#pragma unroll
  for (int m = 0; m < 4; ++m)
#pragma unroll
    for (int n = 0; n < 4; ++n)
#pragma unroll
      for (int r = 0; r < 4; ++r) acc[m][n][r] += bias_n[n];

  if constexpr (EPI == 0) {
    const int sec = colBase >> 10;      // 0=q 1=k 2=v
    if (sec < 2) {
      // l2-normalize rows over this wave's 64 cols (= one head dim)
#pragma unroll
      for (int m = 0; m < 4; ++m)
#pragma unroll
        for (int r = 0; r < 4; ++r) {
          float ss = 0.f;
#pragma unroll
          for (int n = 0; n < 4; ++n) { float x = acc[m][n][r]; ss += x*x; }
          ss += __shfl_xor(ss, 1);
          ss += __shfl_xor(ss, 2);
          ss += __shfl_xor(ss, 4);
          ss += __shfl_xor(ss, 8);
          float inv = 1.0f / fmaxf(sqrtf(ss), 1e-12f);
#pragma unroll
          for (int n = 0; n < 4; ++n) acc[m][n][r] *= inv;
        }
    }
    unsigned short* dst = (sec == 0) ? q_out : ((sec == 1) ? k_out : v_out);
    const int h = (colBase & 1023) >> 6;
#pragma unroll
    for (int m = 0; m < 4; ++m)
#pragma unroll
      for (int r = 0; r < 4; ++r) {
        int mrow = rBase + m*16 + g*4 + r;          // n*L + l
        int nidx = mrow >> 10, li = mrow & 1023;
        size_t base = (((size_t)(nidx*16 + h))*1024 + li)*64;
#pragma unroll
        for (int n = 0; n < 4; ++n)
          dst[base + n*16 + l15] = f2bf(acc[m][n][r]);
      }
  } else {
#pragma unroll
    for (int m = 0; m < 4; ++m)
#pragma unroll
      for (int r = 0; r < 4; ++r) {
        int mrow = rBase + m*16 + g*4 + r;
#pragma unroll
        for (int n = 0; n < 4; ++n)
          f_out[(size_t)mrow*NCOLS + colBase + n*16 + l15] = acc[m][n][r];
      }
  }
}

// ---------------- attention: one (n,h,qblock-of-64) per block ----------------
// logits = 10*cos in [-10,10] -> one-pass softmax, no max subtraction needed.
__global__ __launch_bounds__(256)
void attn_k(const unsigned short* __restrict__ qh,
            const unsigned short* __restrict__ kh,
            const unsigned short* __restrict__ vh,
            const float* __restrict__ logit_scale,
            unsigned short* __restrict__ ao)
{
  __shared__ unsigned short Ks [64*64];    // [k][d] XOR-swizzled, 8KB
  __shared__ unsigned short VTs[64*64];    // [d][k] XOR-swizzled, 8KB
  __shared__ unsigned short Ps [4][16*64]; // per-wave P tile, swizzled, 8KB
  const int bid = blockIdx.x;              // 1024 = N*H * (L/64)
  const int nh = bid >> 4, qb = bid & 15;
  const int h = nh & 15;
  const int tid = threadIdx.x;
  const int w = tid >> 6, lane = tid & 63;
  const int l15 = lane & 15, g = lane >> 4;
  const float s = __expf(fminf(logit_scale[h], 4.6051701859880914f)); // min(ls, log 100)

  const unsigned short* Qb = qh + ((size_t)nh*1024 + qb*64) * 64;
  const unsigned short* Kb = kh + (size_t)nh * 1024 * 64;
  const unsigned short* Vb = vh + (size_t)nh * 1024 * 64;

  // Q fragments in registers: wave w owns q rows w*16..w*16+15
  bf16x8 qf[2];
#pragma unroll
  for (int kk = 0; kk < 2; ++kk)
    qf[kk] = *(const bf16x8*)(Qb + (w*16 + l15)*64 + kk*32 + g*8);

  const f32x4 fzero = {0.f, 0.f, 0.f, 0.f};
  f32x4 oacc[4];
#pragma unroll
  for (int n = 0; n < 4; ++n) oacc[n] = fzero;
  float rs[4] = {0.f, 0.f, 0.f, 0.f};

  for (int kt = 0; kt < 16; ++kt) {
    // stage K tile via global_load_lds with pre-swizzled SOURCE (rule #21)
#pragma unroll
    for (int j = 0; j < 2; ++j) {
      int off = j*4096 + tid*16;
      int r = off >> 7, cbyte = off & 127;
      int scb = cbyte ^ ((r & 7) << 4);
      gload_lds16((const char*)(Kb + (size_t)(kt*64 + r) * 64) + scb, (char*)Ks + off);
    }
    // stage V transposed (coalesced global read, swizzled scalar LDS writes)
#pragma unroll
    for (int j2 = 0; j2 < 2; ++j2) {
      int k  = (tid >> 3) + j2*32;
      int d0 = (tid & 7) * 8;
      u16x8 v = *(const u16x8*)(Vb + (size_t)(kt*64 + k) * 64 + d0);
#pragma unroll
      for (int e = 0; e < 8; ++e) {
        int row = d0 + e;
        *(unsigned short*)((char*)VTs + row*128 + ((k*2) ^ ((row & 7) << 4))) = v[e];
      }
    }
    __syncthreads();

    // S = Q * K^T   (M=16 q rows, N=64 k cols, K-dim = d)
    f32x4 sf[4];
#pragma unroll
    for (int n = 0; n < 4; ++n) sf[n] = fzero;
#pragma unroll
    for (int n = 0; n < 4; ++n) {
      int krow = n*16 + l15;
      int sw = (krow & 7) << 4;
#pragma unroll
      for (int kk = 0; kk < 2; ++kk) {
        bf16x8 bfr = *(const bf16x8*)((const char*)Ks + krow*128 + ((kk*64 + g*16) ^ sw));
        sf[n] = __builtin_amdgcn_mfma_f32_16x16x32_bf16(qf[kk], bfr, sf[n], 0, 0, 0);
      }
    }

    // P = exp(s*S); accumulate row sums; stash P (C-layout -> A-frag via per-wave LDS)
#pragma unroll
    for (int n = 0; n < 4; ++n)
#pragma unroll
      for (int r = 0; r < 4; ++r) {
        float p = __expf(s * sf[n][r]);
        rs[r] += p;
        int prow = g*4 + r;
        *(unsigned short*)((char*)Ps[w] + prow*128 + (((n*16 + l15)*2) ^ ((prow & 7) << 4))) = f2bf(p);
      }

    // O += P * V   (same-wave LDS RAW on Ps: DS pipe is in-order per wave)
#pragma unroll
    for (int kk = 0; kk < 2; ++kk) {
      int swp = (l15 & 7) << 4;
      bf16x8 af = *(const bf16x8*)((const char*)Ps[w] + l15*128 + ((kk*64 + g*16) ^ swp));
#pragma unroll
      for (int n = 0; n < 4; ++n) {
        int vrow = n*16 + l15;
        bf16x8 bfv = *(const bf16x8*)((const char*)VTs + vrow*128 + ((kk*64 + g*16) ^ ((vrow & 7) << 4)));
        oacc[n] = __builtin_amdgcn_mfma_f32_16x16x32_bf16(af, bfv, oacc[n], 0, 0, 0);
      }
    }
    __syncthreads();
  }

#pragma unroll
  for (int r = 0; r < 4; ++r) {
    rs[r] += __shfl_xor(rs[r], 1);
    rs[r] += __shfl_xor(rs[r], 2);
    rs[r] += __shfl_xor(rs[r], 4);
    rs[r] += __shfl_xor(rs[r], 8);
  }
  const int nidx = nh >> 4;
#pragma unroll
  for (int r = 0; r < 4; ++r) {
    float inv = 1.0f / rs[r];
    int qrow = qb*64 + w*16 + g*4 + r;
    size_t rowoff = (size_t)(nidx*1024 + qrow) * 1024 + h*64;
#pragma unroll
    for (int n = 0; n < 4; ++n)
      ao[rowoff + n*16 + l15] = f2bf(oacc[n][r] * inv);
  }
}

// ---------------- launch ----------------
extern "C" void kernel_launch(void* const* d_in, const int* in_sizes, int n_in,
                              void* d_out, int out_size, void* d_ws, size_t ws_size,
                              hipStream_t stream) {
  const float* x    = (const float*)d_in[0];
  const float* Wqkv = (const float*)d_in[1];
  const float* bqkv = (const float*)d_in[2];
  const float* Aq   = (const float*)d_in[3];
  const float* Bq   = (const float*)d_in[4];
  const float* Ak   = (const float*)d_in[5];
  const float* Bk   = (const float*)d_in[6];
  const float* Av   = (const float*)d_in[7];
  const float* Bv   = (const float*)d_in[8];
  const float* ls   = (const float*)d_in[9];
  const float* Wout = (const float*)d_in[10];
  const float* bout = (const float*)d_in[11];
  float* out = (float*)d_out;

  char* ws = (char*)d_ws;
  unsigned short* xb   = (unsigned short*)(ws);                      // 8 MB (x bf16; later reused as attn_out)
  unsigned short* weff = (unsigned short*)(ws + (8u  << 20));        // 6 MB
  unsigned short* wob  = (unsigned short*)(ws + (14u << 20));        // 2 MB
  unsigned short* qhp  = (unsigned short*)(ws + (16u << 20));        // 8 MB [N,H,L,64]
  unsigned short* khp  = (unsigned short*)(ws + (24u << 20));        // 8 MB
  unsigned short* vhp  = (unsigned short*)(ws + (32u << 20));        // 8 MB
  unsigned short* aop  = xb;  // xb dead after GEMM1 -> reuse for attention output

  cvt_k <<<4096, 256, 0, stream>>>(x, xb, 1048576);         // 4M f32 -> bf16
  cvt_k <<<1024, 256, 0, stream>>>(Wout, wob, 262144);      // 1M
  weff_k<<<12288, 256, 0, stream>>>(Wqkv, Aq, Bq, Ak, Bk, Av, Bv, weff);

  gemm_k<3072, 0><<<768, 256, 0, stream>>>(xb, weff, bqkv, qhp, khp, vhp, nullptr);
  attn_k<<<1024, 256, 0, stream>>>(qhp, khp, vhp, ls, aop);
  gemm_k<1024, 1><<<256, 256, 0, stream>>>(aop, wob, bout, nullptr, nullptr, nullptr, out);
}

// Round 8
// 202.972 us; speedup vs baseline: 1.0839x; 1.0839x over previous
//
#include <hip/hip_runtime.h>
#include <hip/hip_bf16.h>
#include <cstdint>
#include <cstddef>

#define DEVI __device__ __forceinline__

typedef __attribute__((ext_vector_type(8))) short bf16x8;   // 8 bf16 in 4 VGPRs (guide §3)
typedef __attribute__((ext_vector_type(4))) float f32x4;
typedef __attribute__((ext_vector_type(8))) unsigned short u16x8;

// round-to-nearest-even f32 -> bf16 bits
DEVI unsigned short f2bf(float f) {
  union { float f; unsigned int u; } v; v.f = f;
  unsigned int r = v.u + 0x7FFFu + ((v.u >> 16) & 1u);
  return (unsigned short)(r >> 16);
}

DEVI void gload_lds16(const void* g, void* l) {
  __builtin_amdgcn_global_load_lds((const __attribute__((address_space(1))) void*)g,
                                   (__attribute__((address_space(3))) void*)l,
                                   16, 0, 0);
}

// ---------------- prep: f32 -> bf16 convert (vectorized) ----------------
__global__ void cvt_k(const float* __restrict__ in, unsigned short* __restrict__ out, int n4) {
  int i = blockIdx.x * 256 + threadIdx.x;
  if (i >= n4) return;
  float4 v = reinterpret_cast<const float4*>(in)[i];
  ushort4 o;
  o.x = f2bf(v.x); o.y = f2bf(v.y); o.z = f2bf(v.z); o.w = f2bf(v.w);
  reinterpret_cast<ushort4*>(out)[i] = o;
}

// ---------------- prep: W_eff = W_qkv + 2 * B @ A  (LoRA folded) ----------------
__global__ void weff_k(const float* __restrict__ W,
                       const float* __restrict__ Aq, const float* __restrict__ Bq,
                       const float* __restrict__ Ak, const float* __restrict__ Bk,
                       const float* __restrict__ Av, const float* __restrict__ Bv,
                       unsigned short* __restrict__ out) {
  int idx = blockIdx.x * 256 + threadIdx.x;   // 3072*1024 total
  int o = idx >> 10, c = idx & 1023;
  const float* A; const float* B; int ol;
  if (o < 1024)      { A = Aq; B = Bq; ol = o; }
  else if (o < 2048) { A = Ak; B = Bk; ol = o - 1024; }
  else               { A = Av; B = Bv; ol = o - 2048; }
  float acc = W[idx];
#pragma unroll
  for (int r = 0; r < 8; ++r) acc += 2.0f * B[ol*8 + r] * A[r*1024 + c];
  out[idx] = f2bf(acc);
}

// ---------------- GEMM: C[M,NCOLS] = A[M,1024] * Bw[NCOLS,1024]^T ----------------
// EPI=0: +bias, l2-normalize q/k over 64-col head chunks, scatter to [N,H,L,64] bf16
// EPI=1: +bias, write fp32 [M,NCOLS]
template<int NCOLS, int EPI>
__global__ __launch_bounds__(256)
void gemm_k(const unsigned short* __restrict__ A,
            const unsigned short* __restrict__ Bw,
            const float* __restrict__ bias,
            unsigned short* __restrict__ q_out,
            unsigned short* __restrict__ k_out,
            unsigned short* __restrict__ v_out,
            float* __restrict__ f_out)
{
  constexpr int K = 1024;
  constexpr int NBN = NCOLS / 128;
  __shared__ unsigned short As[128*32];   // 8 KB, row-major [128][32] bf16
  __shared__ unsigned short Bs[128*32];
  const int bid  = blockIdx.x;
  const int bn   = bid % NBN, bm = bid / NBN;
  const int tid  = threadIdx.x;
  const int lane = tid & 63, wave = tid >> 6;
  const int wr = wave >> 1, wc = wave & 1;     // 2x2 wave grid, 64x64 each
  const int l15 = lane & 15, g = lane >> 4;

  const f32x4 fzero = {0.f, 0.f, 0.f, 0.f};
  f32x4 acc[4][4];
#pragma unroll
  for (int m = 0; m < 4; ++m)
#pragma unroll
    for (int n = 0; n < 4; ++n) acc[m][n] = fzero;

  for (int k0 = 0; k0 < K; k0 += 32) {
#pragma unroll
    for (int j = 0; j < 2; ++j) {
      int off = j*4096 + tid*16;            // linear byte offset in 8KB tile
      int r = off >> 6, cb = off & 63;      // row (64B rows), col byte
      gload_lds16((const char*)(A  + (size_t)(bm*128 + r) * K) + k0*2 + cb, (char*)As + off);
      gload_lds16((const char*)(Bw + (size_t)(bn*128 + r) * K) + k0*2 + cb, (char*)Bs + off);
    }
    __syncthreads();   // drains vmcnt for global_load_lds
    bf16x8 af[4], bfr[4];
#pragma unroll
    for (int m = 0; m < 4; ++m)
      af[m] = *(const bf16x8*)((const char*)As + (wr*64 + m*16 + l15)*64 + g*16);
#pragma unroll
    for (int n = 0; n < 4; ++n)
      bfr[n] = *(const bf16x8*)((const char*)Bs + (wc*64 + n*16 + l15)*64 + g*16);
#pragma unroll
    for (int m = 0; m < 4; ++m)
#pragma unroll
      for (int n = 0; n < 4; ++n)
        acc[m][n] = __builtin_amdgcn_mfma_f32_16x16x32_bf16(af[m], bfr[n], acc[m][n], 0, 0, 0);
    __syncthreads();
  }

  const int colBase = bn*128 + wc*64;   // one 64-col head chunk per wave
  const int rBase   = bm*128 + wr*64;
  float bias_n[4];
#pragma unroll
  for (int n = 0; n < 4; ++n) bias_n[n] = bias[colBase + n*16 + l15];
#pragma unroll
  for (int m = 0; m < 4; ++m)
#pragma unroll
    for (int n = 0; n < 4; ++n)
#pragma unroll
      for (int r = 0; r < 4; ++r) acc[m][n][r] += bias_n[n];

  if constexpr (EPI == 0) {
    const int sec = colBase >> 10;      // 0=q 1=k 2=v
    if (sec < 2) {
      // l2-normalize rows over this wave's 64 cols (= one head dim)
#pragma unroll
      for (int m = 0; m < 4; ++m)
#pragma unroll
        for (int r = 0; r < 4; ++r) {
          float ss = 0.f;
#pragma unroll
          for (int n = 0; n < 4; ++n) { float x = acc[m][n][r]; ss += x*x; }
          ss += __shfl_xor(ss, 1);
          ss += __shfl_xor(ss, 2);
          ss += __shfl_xor(ss, 4);
          ss += __shfl_xor(ss, 8);
          float inv = 1.0f / fmaxf(sqrtf(ss), 1e-12f);
#pragma unroll
          for (int n = 0; n < 4; ++n) acc[m][n][r] *= inv;
        }
    }
    unsigned short* dst = (sec == 0) ? q_out : ((sec == 1) ? k_out : v_out);
    const int h = (colBase & 1023) >> 6;
#pragma unroll
    for (int m = 0; m < 4; ++m)
#pragma unroll
      for (int r = 0; r < 4; ++r) {
        int mrow = rBase + m*16 + g*4 + r;          // n*L + l
        int nidx = mrow >> 10, li = mrow & 1023;
        size_t base = (((size_t)(nidx*16 + h))*1024 + li)*64;
#pragma unroll
        for (int n = 0; n < 4; ++n)
          dst[base + n*16 + l15] = f2bf(acc[m][n][r]);
      }
  } else {
#pragma unroll
    for (int m = 0; m < 4; ++m)
#pragma unroll
      for (int r = 0; r < 4; ++r) {
        int mrow = rBase + m*16 + g*4 + r;
#pragma unroll
        for (int n = 0; n < 4; ++n)
          f_out[(size_t)mrow*NCOLS + colBase + n*16 + l15] = acc[m][n][r];
      }
  }
}

// ---------------- attention: one (n,h,qblock-of-64) per block ----------------
// logits = 10*cos in [-10,10] -> one-pass softmax, no max subtraction needed.
// Swizzles (round 6): VTs uses ((row^(row>>3))&7)<<4 -- write lanes vary row>>3,
// read lanes vary row&7, XOR spreads both to 2-way (free). Ps uses ((row>>2)&3)<<5
// -- write sw=g<<5 disjoint 8-bank sets, read slot-spread verified.
__global__ __launch_bounds__(256)
void attn_k(const unsigned short* __restrict__ qh,
            const unsigned short* __restrict__ kh,
            const unsigned short* __restrict__ vh,
            const float* __restrict__ logit_scale,
            unsigned short* __restrict__ ao)
{
  __shared__ unsigned short Ks [64*64];    // [k][d] XOR-swizzled, 8KB
  __shared__ unsigned short VTs[64*64];    // [d][k] XOR-swizzled, 8KB
  __shared__ unsigned short Ps [4][16*64]; // per-wave P tile, swizzled, 8KB
  // XCD-aware remap: all 16 q-tiles of one (n,h) on one XCD (xcd = bid%8 heuristic)
  const int bid = blockIdx.x;              // 1024 = N*H * (L/64)
  const int xcd = bid & 7, slot = bid >> 3;
  const int nh = xcd + ((slot >> 4) << 3);
  const int qb = slot & 15;
  const int h = nh & 15;
  const int tid = threadIdx.x;
  const int w = tid >> 6, lane = tid & 63;
  const int l15 = lane & 15, g = lane >> 4;
  const float s = __expf(fminf(logit_scale[h], 4.6051701859880914f)); // min(ls, log 100)

  const unsigned short* Qb = qh + ((size_t)nh*1024 + qb*64) * 64;
  const unsigned short* Kb = kh + (size_t)nh * 1024 * 64;
  const unsigned short* Vb = vh + (size_t)nh * 1024 * 64;

  // Q fragments in registers: wave w owns q rows w*16..w*16+15
  bf16x8 qf[2];
#pragma unroll
  for (int kk = 0; kk < 2; ++kk)
    qf[kk] = *(const bf16x8*)(Qb + (w*16 + l15)*64 + kk*32 + g*8);

  const f32x4 fzero = {0.f, 0.f, 0.f, 0.f};
  f32x4 oacc[4];
#pragma unroll
  for (int n = 0; n < 4; ++n) oacc[n] = fzero;
  float rs[4] = {0.f, 0.f, 0.f, 0.f};

  for (int kt = 0; kt < 16; ++kt) {
    // stage K tile via global_load_lds with pre-swizzled SOURCE (rule #21)
#pragma unroll
    for (int j = 0; j < 2; ++j) {
      int off = j*4096 + tid*16;
      int r = off >> 7, cbyte = off & 127;
      int scb = cbyte ^ ((r & 7) << 4);
      gload_lds16((const char*)(Kb + (size_t)(kt*64 + r) * 64) + scb, (char*)Ks + off);
    }
    // stage V transposed (coalesced global read, swizzled scalar LDS writes)
#pragma unroll
    for (int j2 = 0; j2 < 2; ++j2) {
      int k  = (tid >> 3) + j2*32;
      int d0 = (tid & 7) * 8;
      u16x8 v = *(const u16x8*)(Vb + (size_t)(kt*64 + k) * 64 + d0);
#pragma unroll
      for (int e = 0; e < 8; ++e) {
        int row = d0 + e;
        int sw = ((row ^ (row >> 3)) & 7) << 4;
        *(unsigned short*)((char*)VTs + row*128 + ((k*2) ^ sw)) = v[e];
      }
    }
    __syncthreads();

    // S = Q * K^T   (M=16 q rows, N=64 k cols, K-dim = d)
    f32x4 sf[4];
#pragma unroll
    for (int n = 0; n < 4; ++n) sf[n] = fzero;
#pragma unroll
    for (int n = 0; n < 4; ++n) {
      int krow = n*16 + l15;
      int sw = (krow & 7) << 4;
#pragma unroll
      for (int kk = 0; kk < 2; ++kk) {
        bf16x8 bfr = *(const bf16x8*)((const char*)Ks + krow*128 + ((kk*64 + g*16) ^ sw));
        sf[n] = __builtin_amdgcn_mfma_f32_16x16x32_bf16(qf[kk], bfr, sf[n], 0, 0, 0);
      }
    }

    // P = exp(s*S); accumulate row sums; stash P (C-layout -> A-frag via per-wave LDS)
#pragma unroll
    for (int n = 0; n < 4; ++n)
#pragma unroll
      for (int r = 0; r < 4; ++r) {
        float p = __expf(s * sf[n][r]);
        rs[r] += p;
        int prow = g*4 + r;
        int swp = ((prow >> 2) & 3) << 5;
        *(unsigned short*)((char*)Ps[w] + prow*128 + (((n*16 + l15)*2) ^ swp)) = f2bf(p);
      }

    // O += P * V   (same-wave LDS RAW on Ps: DS pipe is in-order per wave)
#pragma unroll
    for (int kk = 0; kk < 2; ++kk) {
      int swp = ((l15 >> 2) & 3) << 5;
      bf16x8 af = *(const bf16x8*)((const char*)Ps[w] + l15*128 + ((kk*64 + g*16) ^ swp));
#pragma unroll
      for (int n = 0; n < 4; ++n) {
        int vrow = n*16 + l15;
        int swv = ((vrow ^ (vrow >> 3)) & 7) << 4;
        bf16x8 bfv = *(const bf16x8*)((const char*)VTs + vrow*128 + ((kk*64 + g*16) ^ swv));
        oacc[n] = __builtin_amdgcn_mfma_f32_16x16x32_bf16(af, bfv, oacc[n], 0, 0, 0);
      }
    }
    __syncthreads();
  }

#pragma unroll
  for (int r = 0; r < 4; ++r) {
    rs[r] += __shfl_xor(rs[r], 1);
    rs[r] += __shfl_xor(rs[r], 2);
    rs[r] += __shfl_xor(rs[r], 4);
    rs[r] += __shfl_xor(rs[r], 8);
  }
  const int nidx = nh >> 4;
#pragma unroll
  for (int r = 0; r < 4; ++r) {
    float inv = 1.0f / rs[r];
    int qrow = qb*64 + w*16 + g*4 + r;
    size_t rowoff = (size_t)(nidx*1024 + qrow) * 1024 + h*64;
#pragma unroll
    for (int n = 0; n < 4; ++n)
      ao[rowoff + n*16 + l15] = f2bf(oacc[n][r] * inv);
  }
}

// ---------------- launch ----------------
extern "C" void kernel_launch(void* const* d_in, const int* in_sizes, int n_in,
                              void* d_out, int out_size, void* d_ws, size_t ws_size,
                              hipStream_t stream) {
  const float* x    = (const float*)d_in[0];
  const float* Wqkv = (const float*)d_in[1];
  const float* bqkv = (const float*)d_in[2];
  const float* Aq   = (const float*)d_in[3];
  const float* Bq   = (const float*)d_in[4];
  const float* Ak   = (const float*)d_in[5];
  const float* Bk   = (const float*)d_in[6];
  const float* Av   = (const float*)d_in[7];
  const float* Bv   = (const float*)d_in[8];
  const float* ls   = (const float*)d_in[9];
  const float* Wout = (const float*)d_in[10];
  const float* bout = (const float*)d_in[11];
  float* out = (float*)d_out;

  char* ws = (char*)d_ws;
  unsigned short* xb   = (unsigned short*)(ws);                      // 8 MB (x bf16; later reused as attn_out)
  unsigned short* weff = (unsigned short*)(ws + (8u  << 20));        // 6 MB
  unsigned short* wob  = (unsigned short*)(ws + (14u << 20));        // 2 MB
  unsigned short* qhp  = (unsigned short*)(ws + (16u << 20));        // 8 MB [N,H,L,64]
  unsigned short* khp  = (unsigned short*)(ws + (24u << 20));        // 8 MB
  unsigned short* vhp  = (unsigned short*)(ws + (32u << 20));        // 8 MB
  unsigned short* aop  = xb;  // xb dead after GEMM1 -> reuse for attention output

  cvt_k <<<4096, 256, 0, stream>>>(x, xb, 1048576);         // 4M f32 -> bf16
  cvt_k <<<1024, 256, 0, stream>>>(Wout, wob, 262144);      // 1M
  weff_k<<<12288, 256, 0, stream>>>(Wqkv, Aq, Bq, Ak, Bk, Av, Bv, weff);

  gemm_k<3072, 0><<<768, 256, 0, stream>>>(xb, weff, bqkv, qhp, khp, vhp, nullptr);
  attn_k<<<1024, 256, 0, stream>>>(qhp, khp, vhp, ls, aop);
  gemm_k<1024, 1><<<256, 256, 0, stream>>>(aop, wob, bout, nullptr, nullptr, nullptr, out);
}